// Round 6
// baseline (200.411 us; speedup 1.0000x reference)
//
#include <hip/hip_runtime.h>

// EAConv: EM-routing neighbor aggregation + temporal blend, fully fused.
// T=3, b=1, n=50000, d=64, m=16, K=4, dd=16.
// R12 = R11 (verified, 114us) + latency pipeline + address-VALU trim:
//  - Software-pipelined gather: t+1 neighbor indices + own-x prefetched
//    early in t; t+1's 4 row-loads issued into REGISTERS right after
//    iter0 (latency hides under iters 1-2); regs dumped to LDS at top of
//    t+1. Same-wave DS ordering makes single-buffer reuse safe.
//  - Second, PLAIN LDS copy of z (row stride 65 floats, bank-decorrelated:
//    writes ~2-way free, column reads conflict-free). Column reads zr[m]
//    become ONE t-invariant vaddr + 16 immediate offsets (saves ~45
//    VALU/lane-t of swizzled address math). Swizzled copy zs kept for the
//    conflict-free row reads (R11-verified pattern).
//  - All LDS addresses hoisted to t-invariant registers (computed once).
// Lane = output dim d=16k+p. zr[m]=z[m][d] col, zrow=z[p][16k..] row,
// u/xh/acc scalar per lane. Cross-lane: u/w rows via wave-private LDS,
// softmax over k via shfl_xor 16/32, norms via 16-lane DPP rowsum.

constexpr int T  = 3;
constexpr int N  = 50000;
constexpr int D  = 64;
constexpr int M  = 16;
constexpr float EPS2 = 1e-24f;  // (1e-12)^2

template <int CTRL>
__device__ __forceinline__ float dpp_add(float v) {
    // mov_dpp with undef old -> GCNDPPCombine fuses into v_add_f32_dpp
    int rot = __builtin_amdgcn_mov_dpp(__float_as_int(v), CTRL, 0xF, 0xF, false);
    return v + __int_as_float(rot);
}
// sum over the 16 lanes of a DPP row; result broadcast within the row
__device__ __forceinline__ float rowsum16(float v) {
    v = dpp_add<0x128>(v);  // row_ror:8
    v = dpp_add<0x124>(v);  // row_ror:4
    v = dpp_add<0x122>(v);  // row_ror:2
    v = dpp_add<0x121>(v);  // row_ror:1
    return v;
}

__global__ __launch_bounds__(256, 4) void eaconv_fused(
    const float* __restrict__ x_all,   // [T,N,D]
    const int*   __restrict__ nbr_all, // [T,N,M]
    float*       __restrict__ out)     // [T,N,D]
{
    __shared__ float zs[4][M * 64];      // 4KB/wave: swizzled (row reads)
    __shared__ float zp[4][M * 65];      // 4.16KB/wave: plain+65 (col reads)
    __shared__ float ub[4][D];           // u broadcast row
    __shared__ float wb[4][D];           // weight broadcast row
    const int wv   = threadIdx.x >> 6;
    const int i    = blockIdx.x * 4 + wv;
    const int lane = threadIdx.x & 63;
    if (i >= N) return;
    const int p  = lane & 15;            // neighbor index for lane scalars
    const int k  = lane >> 4;            // factor
    const int x7 = p & 7;
    char* zsb = (char*)zs[wv];
    char* zpb = (char*)zp[wv];
    float* uw  = ub[wv];
    float* wwp = wb[wv];

    // ---- t-invariant byte addresses (computed once) ----
    const int ve  = 256 * k + 16 * (p ^ k);  // zs write, even c (c=0:+0, c=2:+2048)
    const int vo  = ve ^ 64;                 // zs write, odd c  (c=1:+1024, c=3:+3072)
    const int vpw = 260 * k + 16 * p;        // zp write (stride 65 fl = 260B)
    const int c4  = (4 * k) ^ x7;
    const int rq0 = 256 * p + ((c4 ^ 0) << 4);  // zs row-read granules
    const int rq1 = 256 * p + ((c4 ^ 1) << 4);
    const int rq2 = 256 * p + ((c4 ^ 2) << 4);
    const int rq3 = 256 * p + ((c4 ^ 3) << 4);
    const int colb = 4 * lane;               // zp column-read vaddr
    const int rowb = 64 * k;                 // u/w row-read vaddr

    float acc = 0.f;
    const float s1q = 0.25f * 0.7310585786300049f;  // 0.25*sigmoid(1)

    // ---- prologue: prefetch t=0 ----
    int jc; bool valid; float xv; float4 g0, g1, g2, g3;
    {
        const int jr = nbr_all[(size_t)i * M + p];
        valid = (unsigned)jr < (unsigned)N;
        jc = valid ? jr : 0;
        xv = x_all[(size_t)i * D + lane];
        const int j0 = __shfl(jc,      k, 64), j1 = __shfl(jc,  4 + k, 64),
                  j2 = __shfl(jc,  8 + k, 64), j3 = __shfl(jc, 12 + k, 64);
        g0 = *(const float4*)(x_all + (size_t)j0 * D + 4 * p);
        g1 = *(const float4*)(x_all + (size_t)j1 * D + 4 * p);
        g2 = *(const float4*)(x_all + (size_t)j2 * D + 4 * p);
        g3 = *(const float4*)(x_all + (size_t)j3 * D + 4 * p);
    }

#pragma unroll
    for (int t = 0; t < T; ++t) {
        // ---- stage: gathered rows -> LDS (both copies) ----
        *(float4*)(zsb + ve)         = g0;
        *(float4*)(zsb + vo + 1024)  = g1;
        *(float4*)(zsb + ve + 2048)  = g2;
        *(float4*)(zsb + vo + 3072)  = g3;
        *(float4*)(zpb + vpw)        = g0;
        *(float4*)(zpb + vpw + 1040) = g1;
        *(float4*)(zpb + vpw + 2080) = g2;
        *(float4*)(zpb + vpw + 3120) = g3;

        // ---- prefetch t+1 scalars (independent; issued ASAP) ----
        int jn = 0; bool nvalid = false; float xn = 0.f;
        if (t < T - 1) {
            const int jr = nbr_all[((size_t)(t + 1) * N + i) * M + p];
            nvalid = (unsigned)jr < (unsigned)N;
            jn = nvalid ? jr : 0;
            xn = x_all[((size_t)(t + 1) * N + i) * D + lane];
        }

        // ---- own norm ----
        const float sx = rowsum16(xv * xv);
        const float xh = xv * __builtin_amdgcn_rsqf(fmaxf(sx, EPS2));

        // ---- zrow = z[p][16k..16k+15] (swizzled copy, hoisted addrs) ----
        float zrow[16];
        {
            const float4 v0 = *(const float4*)(zsb + rq0);
            const float4 v1 = *(const float4*)(zsb + rq1);
            const float4 v2 = *(const float4*)(zsb + rq2);
            const float4 v3 = *(const float4*)(zsb + rq3);
            zrow[ 0]=v0.x; zrow[ 1]=v0.y; zrow[ 2]=v0.z; zrow[ 3]=v0.w;
            zrow[ 4]=v1.x; zrow[ 5]=v1.y; zrow[ 6]=v1.z; zrow[ 7]=v1.w;
            zrow[ 8]=v2.x; zrow[ 9]=v2.y; zrow[10]=v2.z; zrow[11]=v2.w;
            zrow[12]=v3.x; zrow[13]=v3.y; zrow[14]=v3.z; zrow[15]=v3.w;
        }
        // ---- zr[m] = z[m][lane] (plain copy: 1 vaddr + imm offsets) ----
        float zr[16];
#pragma unroll
        for (int m = 0; m < 16; ++m)
            zr[m] = *(const float*)(zpb + colb + 260 * m);

        // ---- neighbor norm rz[p][k] (per-lane serial) ----
        float s0 = zrow[0]*zrow[0], s1 = zrow[1]*zrow[1],
              s2 = zrow[2]*zrow[2], s3 = zrow[3]*zrow[3];
#pragma unroll
        for (int q = 4; q < 16; q += 4) {
            s0 = fmaf(zrow[q+0], zrow[q+0], s0);
            s1 = fmaf(zrow[q+1], zrow[q+1], s1);
            s2 = fmaf(zrow[q+2], zrow[q+2], s2);
            s3 = fmaf(zrow[q+3], zrow[q+3], s3);
        }
        float rz = __builtin_amdgcn_rsqf(fmaxf((s0+s1)+(s2+s3), EPS2));
        if (!valid) rz = 0.f;

        // ---- iter 0: u = 4*xh + sum_m rz_m * z[m][d] ----
        wwp[lane] = rz;                  // k*16+p == lane
        float rzr[16];
        {
            const float4 v0 = *(const float4*)((char*)wwp + rowb);
            const float4 v1 = *(const float4*)((char*)wwp + rowb + 16);
            const float4 v2 = *(const float4*)((char*)wwp + rowb + 32);
            const float4 v3 = *(const float4*)((char*)wwp + rowb + 48);
            rzr[ 0]=v0.x; rzr[ 1]=v0.y; rzr[ 2]=v0.z; rzr[ 3]=v0.w;
            rzr[ 4]=v1.x; rzr[ 5]=v1.y; rzr[ 6]=v1.z; rzr[ 7]=v1.w;
            rzr[ 8]=v2.x; rzr[ 9]=v2.y; rzr[10]=v2.z; rzr[11]=v2.w;
            rzr[12]=v3.x; rzr[13]=v3.y; rzr[14]=v3.z; rzr[15]=v3.w;
        }
        float u = xh * 4.0f;
#pragma unroll
        for (int m = 0; m < 16; ++m) u = fmaf(rzr[m], zr[m], u);
        float inv = __builtin_amdgcn_rsqf(fmaxf(rowsum16(u * u), EPS2));
        uw[lane] = u;

        // ---- issue t+1 gather now: latency hides under iters 1-2 ----
        if (t < T - 1) {
            const float* xnp = x_all + (size_t)(t + 1) * N * D;
            const int j0 = __shfl(jn,      k, 64), j1 = __shfl(jn,  4 + k, 64),
                      j2 = __shfl(jn,  8 + k, 64), j3 = __shfl(jn, 12 + k, 64);
            g0 = *(const float4*)(xnp + (size_t)j0 * D + 4 * p);
            g1 = *(const float4*)(xnp + (size_t)j1 * D + 4 * p);
            g2 = *(const float4*)(xnp + (size_t)j2 * D + 4 * p);
            g3 = *(const float4*)(xnp + (size_t)j3 * D + 4 * p);
        }

        // ---- iters 1..2 ----
#pragma unroll
        for (int it = 1; it < 3; ++it) {
            float urow[16];
            {
                const float4 v0 = *(const float4*)((char*)uw + rowb);
                const float4 v1 = *(const float4*)((char*)uw + rowb + 16);
                const float4 v2 = *(const float4*)((char*)uw + rowb + 32);
                const float4 v3 = *(const float4*)((char*)uw + rowb + 48);
                urow[ 0]=v0.x; urow[ 1]=v0.y; urow[ 2]=v0.z; urow[ 3]=v0.w;
                urow[ 4]=v1.x; urow[ 5]=v1.y; urow[ 6]=v1.z; urow[ 7]=v1.w;
                urow[ 8]=v2.x; urow[ 9]=v2.y; urow[10]=v2.z; urow[11]=v2.w;
                urow[12]=v3.x; urow[13]=v3.y; urow[14]=v3.z; urow[15]=v3.w;
            }
            float d0 = zrow[0]*urow[0], d1 = zrow[1]*urow[1],
                  d2 = zrow[2]*urow[2], d3 = zrow[3]*urow[3];
#pragma unroll
            for (int q = 4; q < 16; q += 4) {
                d0 = fmaf(zrow[q+0], urow[q+0], d0);
                d1 = fmaf(zrow[q+1], urow[q+1], d1);
                d2 = fmaf(zrow[q+2], urow[q+2], d2);
                d3 = fmaf(zrow[q+3], urow[q+3], d3);
            }
            const float dot = (d0 + d1) + (d2 + d3);
            const float logit = dot * (rz * inv);   // zhat.uhat in [-1,1]
            const float e = __expf(logit);
            float es = e + __shfl_xor(e, 16, 64);   // softmax over k
            es += __shfl_xor(es, 32, 64);
            const float wf = e * __builtin_amdgcn_rcpf(es) * rz;

            wwp[lane] = wf;
            float wr[16];
            {
                const float4 v0 = *(const float4*)((char*)wwp + rowb);
                const float4 v1 = *(const float4*)((char*)wwp + rowb + 16);
                const float4 v2 = *(const float4*)((char*)wwp + rowb + 32);
                const float4 v3 = *(const float4*)((char*)wwp + rowb + 48);
                wr[ 0]=v0.x; wr[ 1]=v0.y; wr[ 2]=v0.z; wr[ 3]=v0.w;
                wr[ 4]=v1.x; wr[ 5]=v1.y; wr[ 6]=v1.z; wr[ 7]=v1.w;
                wr[ 8]=v2.x; wr[ 9]=v2.y; wr[10]=v2.z; wr[11]=v2.w;
                wr[12]=v3.x; wr[13]=v3.y; wr[14]=v3.z; wr[15]=v3.w;
            }
            u = xh;
#pragma unroll
            for (int m = 0; m < 16; ++m) u = fmaf(wr[m], zr[m], u);
            if (it < 2) {
                inv = __builtin_amdgcn_rsqf(fmaxf(rowsum16(u * u), EPS2));
                uw[lane] = u;
            }
        }

        // ---- temporal blend (scalar) + coalesced store ----
        float wout;
        if (t == 0)      { wout = u; acc = u; }
        else if (t == 1) { wout = 0.25f * acc + 0.5f * u;
                           acc = fmaf(s1q, wout, 0.125f * acc); }
        else             { wout = acc + 0.5f * u; }
        out[((size_t)t * N + i) * D + lane] = wout;

        // ---- rotate pipeline state ----
        jc = jn; valid = nvalid; xv = xn;
    }
}

extern "C" void kernel_launch(void* const* d_in, const int* in_sizes, int n_in,
                              void* d_out, int out_size, void* d_ws, size_t ws_size,
                              hipStream_t stream) {
    const float* x_all = (const float*)d_in[0];
    const int*   nbrs  = (const int*)d_in[1];
    float*       out   = (float*)d_out;

    // one wave per node, 4 waves per block
    const int blocks = (N + 3) / 4;  // 12500
    eaconv_fused<<<blocks, 256, 0, stream>>>(x_all, nbrs, out);
}